// Round 1
// 716.699 us; speedup vs baseline: 4.8837x; 4.8837x over previous
//
#include <hip/hip_runtime.h>
#include <math.h>

#define Bn   4
#define CINn 16
#define HIDn 16
#define Tn   31
#define Hn   128
#define Wn   128

#define NS    14                  // K-steps: 28 taps (27 real + 1 zero-pad) x 16 cin, K=32 each
#define WSTR  48                  // LDS bytes per w-position (16 f16 used + 8 pad) -> 16B aligned, 2-way banks
#define ROWB  (130*WSTR)          // 6240 B per staged row (w = -1..128)
#define SLOTB (3*ROWB)            // 18720 B per time slice (rows h-1..h+1)
#define LDSB  (3*SLOTB)           // 56160 B ring (t-1, t, t+1)

typedef _Float16 half8 __attribute__((ext_vector_type(8)));
typedef float    f32x4 __attribute__((ext_vector_type(4)));

// tap = kd*9 + kh*3 + kw ; entry 27 is an address clamp (its weight is 0)
constexpr int KDt[28] = {0,0,0,0,0,0,0,0,0, 1,1,1,1,1,1,1,1,1, 2,2,2,2,2,2,2,2,2, 2};
constexpr int KHt[28] = {0,0,0,1,1,1,2,2,2, 0,0,0,1,1,1,2,2,2, 0,0,0,1,1,1,2,2,2, 2};
constexpr int KWt[28] = {0,1,2,0,1,2,0,1,2, 0,1,2,0,1,2,0,1,2, 0,1,2,0,1,2,0,1,2, 2};

__device__ __forceinline__ float sigmoidf_(float x) { return 1.f / (1.f + __expf(-x)); }
__device__ __forceinline__ float tanhf_(float x)    { return 2.f / (1.f + __expf(-2.f * x)) - 1.f; }

// Repack W[oc][cin][kd][kh][kw] into per-lane A-fragment layout, f16:
// WA[s][m][lane][j] : s=K-step, m=oc-tile(16), lane 0..63, j 0..7
//   g = lane>>4 ; tap = 2s + (g>>1) ; cin = (g&1)*8 + j ; oc = m*16 + (lane&15)
// One wave's A-frag load is a single coalesced 1024B chunk.
__global__ void repack_wa_kernel(const float* __restrict__ W, _Float16* __restrict__ WA) {
    int idx = blockIdx.x * blockDim.x + threadIdx.x;
    if (idx >= NS * 4 * 64 * 8) return;
    int j    = idx & 7;
    int lane = (idx >> 3) & 63;
    int m    = (idx >> 9) & 3;
    int s    = idx >> 11;
    int g    = lane >> 4;
    int tap  = 2 * s + (g >> 1);
    int cin  = (g & 1) * 8 + j;
    int oc   = m * 16 + (lane & 15);
    float v  = (tap < 27) ? W[(size_t)(oc * CINn + cin) * 27 + tap] : 0.f;
    WA[idx] = (_Float16)v;
}

// One workgroup per (b, h): 256 threads = 4 waves. Implicit-GEMM conv via
// mfma_f32_16x16x32_f16 (M=oc, N=w, K=taps*cin), recurrence fused: c kept in
// registers across t. Rolling 3-slice f16 LDS ring for X (cin-contiguous so a
// B-frag is one ds_read_b128; stride 48B -> conflict-free & 16B aligned).
__global__ __launch_bounds__(256, 2)
void qrnn_mfma_kernel(const float* __restrict__ X, const _Float16* __restrict__ WA,
                      const float* __restrict__ bias, float* __restrict__ out) {
    __shared__ __align__(16) char smem[LDSB];

    const int tid  = threadIdx.x;
    const int lane = tid & 63;
    const int wv   = tid >> 6;            // wave 0..3 -> w segments [wv*32, wv*32+32)

    // XCD-bijective swizzle (512 wgs, 8 XCDs, 512%8==0): contiguous h per XCD L2
    const int swz = (blockIdx.x & 7) * 64 + (blockIdx.x >> 3);
    const int b = swz >> 7;
    const int h = swz & 127;

    const size_t strideT = (size_t)Hn * Wn;        // 16384
    const size_t strideC = (size_t)Tn * strideT;   // 507904
    const float* Xb = X + (size_t)b * CINn * strideC;

    const int lane15  = lane & 15;
    const int g       = lane >> 4;        // k-group 0..3
    const int ghi     = g >> 1;           // which tap of the K-step pair
    const int laneoff = lane15 * WSTR + (g & 1) * 16;
    const int wbase   = wv * 32;

    // bias per thread: hid = g*4 + r (C-frag row = (lane>>4)*4 + reg)
    float bz[4], bfv[4], bov[4], biv[4];
    #pragma unroll
    for (int r = 0; r < 4; r++) {
        int hid = g * 4 + r;
        bz[r]  = bias[hid];
        bfv[r] = bias[HIDn + hid];
        bov[r] = bias[2 * HIDn + hid];
        biv[r] = bias[3 * HIDn + hid];
    }

    // Stage time slice u (rows h-1..h+1, all cin, w halo) into ring slot u%3.
    // Thread owns (row,wpos) pairs; gathers 16 cin (coalesced across lanes) and
    // writes two ds_write_b128 (cin-contiguous layout).
    auto stage = [&](int u) {
        char* sl = smem + (((u % 3) + 3) % 3) * SLOTB;
        const bool uok = (u >= 0) && (u < Tn);
        for (int p = tid; p < 3 * 130; p += 256) {
            int row  = (p >= 260) ? 2 : (p >= 130) ? 1 : 0;
            int wpos = p - row * 130;
            int hr = h - 1 + row;
            int wa = wpos - 1;
            bool valid = uok && (hr >= 0) && (hr < Hn) && (wa >= 0) && (wa < Wn);
            const float* src = Xb + (ptrdiff_t)u * (ptrdiff_t)strideT
                                  + (ptrdiff_t)hr * Wn + wa;
            half8 h0, h1;
            #pragma unroll
            for (int c8 = 0; c8 < 8; c8++)
                h0[c8] = valid ? (_Float16)src[(size_t)c8 * strideC] : (_Float16)0.f;
            #pragma unroll
            for (int c8 = 0; c8 < 8; c8++)
                h1[c8] = valid ? (_Float16)src[(size_t)(8 + c8) * strideC] : (_Float16)0.f;
            char* dst = sl + row * ROWB + wpos * WSTR;
            *reinterpret_cast<half8*>(dst)      = h0;
            *reinterpret_cast<half8*>(dst + 16) = h1;
        }
    };

    float cst[2][4];
    #pragma unroll
    for (int n = 0; n < 2; n++)
        #pragma unroll
        for (int r = 0; r < 4; r++) cst[n][r] = 0.f;

    float* outT = out + (size_t)b * HIDn * strideC + (size_t)h * Wn + wbase + lane15;

    stage(-1);     // zeros
    stage(0);

    for (int t = 0; t < Tn; t++) {
        stage(t + 1);                       // slot (t+1)%3 ; u=31 stages zeros
        __syncthreads();

        // ring slot byte-bases for kd = 0,1,2  (slices t-1, t, t+1)
        const int sb[3] = { ((t + 2) % 3) * SLOTB, (t % 3) * SLOTB, ((t + 1) % 3) * SLOTB };

        f32x4 acc[2][4];
        #pragma unroll
        for (int n = 0; n < 2; n++)
            #pragma unroll
            for (int m = 0; m < 4; m++) acc[n][m] = (f32x4)(0.f);

        #pragma unroll
        for (int s = 0; s < NS; s++) {
            // A-frags: 4 oc-tiles, wave-coalesced 1024B each; L1/L2-resident
            const half8 a0 = *reinterpret_cast<const half8*>(WA + ((size_t)(s * 4 + 0) * 64 + lane) * 8);
            const half8 a1 = *reinterpret_cast<const half8*>(WA + ((size_t)(s * 4 + 1) * 64 + lane) * 8);
            const half8 a2 = *reinterpret_cast<const half8*>(WA + ((size_t)(s * 4 + 2) * 64 + lane) * 8);
            const half8 a3 = *reinterpret_cast<const half8*>(WA + ((size_t)(s * 4 + 3) * 64 + lane) * 8);

            const int tA = 2 * s, tB = 2 * s + 1;        // compile-time
            const int offA = sb[KDt[tA]] + KHt[tA] * ROWB + KWt[tA] * WSTR;
            const int offB = sb[KDt[tB]] + KHt[tB] * ROWB + KWt[tB] * WSTR;
            const int off  = (ghi ? offB : offA) + laneoff;

            #pragma unroll
            for (int n = 0; n < 2; n++) {
                const half8 bf = *reinterpret_cast<const half8*>(
                    smem + off + (wbase + n * 16) * WSTR);
                acc[n][0] = __builtin_amdgcn_mfma_f32_16x16x32_f16(a0, bf, acc[n][0], 0, 0, 0);
                acc[n][1] = __builtin_amdgcn_mfma_f32_16x16x32_f16(a1, bf, acc[n][1], 0, 0, 0);
                acc[n][2] = __builtin_amdgcn_mfma_f32_16x16x32_f16(a2, bf, acc[n][2], 0, 0, 0);
                acc[n][3] = __builtin_amdgcn_mfma_f32_16x16x32_f16(a3, bf, acc[n][3], 0, 0, 0);
            }
        }

        // epilogue: oc-tile m holds gate m (z,f,o,i) for hid = g*4+r, col = w.
        #pragma unroll
        for (int n = 0; n < 2; n++) {
            #pragma unroll
            for (int r = 0; r < 4; r++) {
                float z = tanhf_   (acc[n][0][r] + bz[r]);
                float f = sigmoidf_(acc[n][1][r] + bfv[r]);
                float o = sigmoidf_(acc[n][2][r] + bov[r]);
                float i = sigmoidf_(acc[n][3][r] + biv[r]);
                float c = f * cst[n][r] + i * z;
                cst[n][r] = c;
                outT[(size_t)(g * 4 + r) * strideC + (size_t)t * strideT + n * 16] = o * c;
            }
        }
        __syncthreads();   // protect ring slot reused by next t's stage
    }
}

extern "C" void kernel_launch(void* const* d_in, const int* in_sizes, int n_in,
                              void* d_out, int out_size, void* d_ws, size_t ws_size,
                              hipStream_t stream) {
    const float* X    = (const float*)d_in[0];
    const float* W    = (const float*)d_in[1];
    const float* bias = (const float*)d_in[2];
    float* out = (float*)d_out;
    _Float16* WA = (_Float16*)d_ws;   // 14*4*64*8 f16 = 57344 B

    repack_wa_kernel<<<(NS * 4 * 64 * 8 + 255) / 256, 256, 0, stream>>>(W, WA);
    qrnn_mfma_kernel<<<Bn * Hn, 256, 0, stream>>>(X, WA, bias, out);
}